// Round 15
// baseline (90.304 us; speedup 1.0000x reference)
//
#include <hip/hip_runtime.h>
#include <hip/hip_bf16.h>

#define T_LEN 48000
#define NCH   64
#define NB    4
#define CT    96     // scan chunk length (96000/96 = 1000 chunks; ear boundary = chunk 500)
#define WU    128    // scan warm-up (0.96^128=5.4e-3 -> s err ~0.47; thr err -> spike flips only)
#define TTILE 256    // conv time-span per block (16 MFMA tiles per wave, ring of 16)

static constexpr double DTd    = 1.0 / 48000.0;
static constexpr double ALPHAd = DTd / (DTd + 0.0005);   // exactly 0.04
static constexpr float  AF     = (float)ALPHAd;
static constexpr float  OMF    = (float)(1.0 - ALPHAd);  // 0.96

typedef __attribute__((ext_vector_type(8))) short bf16x8;
typedef __attribute__((ext_vector_type(4))) float f32x4;
typedef bf16x8 bf16x8_u __attribute__((aligned(4)));     // 4B-aligned 16B load

static __device__ __forceinline__ unsigned short f2bf(float f) {
    __hip_bfloat16 h = __float2bfloat16(f);
    unsigned short u; __builtin_memcpy(&u, &h, 2);
    return u;
}

// ---------------------------------------------------------------- K0: fused prep
// role 0..3: Afrag swizzle for group g (+kstart); role 4: x -> parity bf16 copies
__global__ __launch_bounds__(256) void prep_all(
        const float* __restrict__ x, const float* __restrict__ Km,
        int* __restrict__ kstart, unsigned short* __restrict__ xc,
        unsigned short* __restrict__ Afrag,
        int L, int SMAX16, int SMAXA, int PAD, int XCAP) {
    const int role = blockIdx.y;
    if (role < 4) {
        const int g = role, s = blockIdx.x;
        if (s >= SMAX16) return;
        __shared__ int smin;
        if (threadIdx.x == 0) smin = L - 1;
        __syncthreads();
        const float* row = Km + (size_t)(g * 16) * L;
        int local = L - 1;
        for (int i = threadIdx.x; i < L; i += 256)
            if (row[i] != 0.0f) { local = i; break; }
        atomicMin(&smin, local);
        __syncthreads();
        const int ks = smin;
        if (s == 0 && threadIdx.x == 0) kstart[g * 16] = ks;
        if (threadIdx.x < 64) {
            const int lane = threadIdx.x;
            const int Lg = L - ks;
            const int r = lane & 15, khi = lane >> 4;
            const float* kr = Km + (size_t)(g * 16 + r) * L + ks;
            const size_t off = ((size_t)(g * SMAXA + s) * 64 + lane) * 8;
            #pragma unroll
            for (int jj = 0; jj < 8; ++jj) {
                const int q = 32 * s + 8 * khi + jj;
                Afrag[off + jj] = (q < Lg) ? f2bf(kr[q]) : (unsigned short)0;
            }
        }
    } else {
        const int idx = blockIdx.x * 256 + threadIdx.x;
        if (idx >= NB * XCAP) return;
        const int b = idx / XCAP, j = idx % XCAP;
        const float* xb = x + (size_t)b * T_LEN;
        const int t0 = j - PAD, t1 = t0 + 1;
        xc[((size_t)b * 2 + 0) * XCAP + j] = (t0 >= 0 && t0 < T_LEN) ? f2bf(xb[t0]) : (unsigned short)0;
        xc[((size_t)b * 2 + 1) * XCAP + j] = (t1 >= 0 && t1 < T_LEN) ? f2bf(xb[t1]) : (unsigned short)0;
    }
}

// ---------------------------------------------------------------- conv body -> rectT [T][C*4+B]
// R10-proven structure: 16 time-tiles/wave, ring of 16 B-windows, refills issued
// right after the two releasing MFMAs, A staged via double-buffered LDS.
// PHASE = K-steps per barrier phase (8 or 16; both satisfy 2*PHASE % 16 == 0 so
// the slot map (2U+j)&15 is phase-invariant). g0 uses PHASE=16 (halves barriers,
// no extra padding: 89->96 either way); g1-3 keep PHASE=8 (16-padding would add work).
#define GROUP(areg, U)                                                                   \
    acc[0] = __builtin_amdgcn_mfma_f32_16x16x32_bf16(areg, bx[(2*(U))     & 15], acc[0], 0, 0, 0); \
    acc[1] = __builtin_amdgcn_mfma_f32_16x16x32_bf16(areg, bx[(2*(U) + 1) & 15], acc[1], 0, 0, 0); \
    bx[(2*(U))     & 15] = *(const bf16x8_u*)(xp + 256 + 32 * (U));                      \
    bx[(2*(U) + 1) & 15] = *(const bf16x8_u*)(xp + 272 + 32 * (U));                      \
    _Pragma("unroll")                                                                    \
    for (int j = 2; j < 16; ++j)                                                         \
        acc[j] = __builtin_amdgcn_mfma_f32_16x16x32_bf16(areg, bx[(2*(U) + j) & 15], acc[j], 0, 0, 0);

#define HALF(h)                                                                          \
    {                                                                                    \
        const bf16x8 a0 = *(const bf16x8*)(&Ab[(4*(h) + 0) * 512 + lane * 8]);           \
        const bf16x8 a1 = *(const bf16x8*)(&Ab[(4*(h) + 1) * 512 + lane * 8]);           \
        const bf16x8 a2 = *(const bf16x8*)(&Ab[(4*(h) + 2) * 512 + lane * 8]);           \
        const bf16x8 a3 = *(const bf16x8*)(&Ab[(4*(h) + 3) * 512 + lane * 8]);           \
        GROUP(a0, 4*(h) + 0)                                                             \
        GROUP(a1, 4*(h) + 1)                                                             \
        GROUP(a2, 4*(h) + 2)                                                             \
        GROUP(a3, 4*(h) + 3)                                                             \
    }

template <int PHASE>
__device__ __forceinline__ void conv_body(
        const unsigned short* __restrict__ xc, const unsigned short* __restrict__ Afrag,
        unsigned short* __restrict__ rectT, short* smem,
        int L, int SMAXA, int PAD, int XCAP, int g, int t0, int ks) {
    constexpr int RW = PHASE / 4;                      // A rows staged per wave per phase
    const int lane = threadIdx.x & 63;
    const int w    = threadIdx.x >> 6;                 // wave = batch
    const int Lg   = L - ks;
    const int nst  = (Lg + 31) >> 5;
    const int nstP = ((nst + PHASE - 1) / PHASE) * PHASE;
    const int nl   = lane & 15, khi = lane >> 4;
    const int i0   = t0 + nl + 8 * khi - (Lg - 1);     // x index for (K-step 0, tile 0)
    const int p    = i0 & 1;                           // parity fixed across steps/tiles
    const unsigned short* xp  = xc + ((size_t)(w * 2 + p)) * XCAP + (PAD + i0 - p);
    // wave w stages A K-step rows (s + RW*w .. s + RW*w + RW-1)
    const unsigned short* apw = Afrag + ((size_t)(g * SMAXA) + RW * w) * 512 + (size_t)lane * 8;
    short* As = smem;                                  // As[2][PHASE*512] shorts

    f32x4 acc[16];
    #pragma unroll
    for (int j = 0; j < 16; ++j) acc[j] = (f32x4){0.f, 0.f, 0.f, 0.f};
    bf16x8 bx[16];
    #pragma unroll
    for (int j = 0; j < 16; ++j) bx[j] = *(const bf16x8_u*)(xp + 16 * j);

    // initial stage: K-step rows 0..PHASE-1
    #pragma unroll
    for (int r = 0; r < RW; ++r)
        *(bf16x8*)(&As[(RW * w + r) * 512 + lane * 8]) = *(const bf16x8*)(apw + (size_t)r * 512);
    __syncthreads();

    int q = 0;
    for (int s = 0; s < nstP; s += PHASE) {
        // prefetch next phase's A rows (guard rows exist beyond nstP)
        bf16x8 nf[RW];
        #pragma unroll
        for (int r = 0; r < RW; ++r)
            nf[r] = *(const bf16x8*)(apw + (size_t)(s + PHASE + r) * 512);
        const short* Ab = As + q * (PHASE * 512);
        HALF(0)
        HALF(1)
        if constexpr (PHASE == 16) {
            HALF(2)
            HALF(3)
        }
        // stage next phase's A rows into the other buffer, block-wide handoff
        #pragma unroll
        for (int r = 0; r < RW; ++r)
            *(bf16x8*)(&As[(q ^ 1) * (PHASE * 512) + (RW * w + r) * 512 + lane * 8]) = nf[r];
        __syncthreads();
        q ^= 1;
        xp += 32 * PHASE;                              // PHASE K-steps x 32 taps
    }

    // ---- epilogue: acc -> S[t_local][(c_local)*4 + b] -> rectT rows ----
    // D layout: col(time)=lane&15, row(channel)=4*(lane>>4)+v  [m89-verified]
    short* S = smem;                                   // stride 72 shorts/row (16B-mult)
    #pragma unroll
    for (int j = 0; j < 16; ++j) {
        #pragma unroll
        for (int v = 0; v < 4; ++v)
            S[(16 * j + nl) * 72 + (4 * khi + v) * 4 + w] =
                (short)f2bf(fmaxf(acc[j][v], 0.f));
    }
    __syncthreads();
    {   // cooperative copy: 8 iters x 32 rows; 128B contiguous per row-segment
        const int rr = threadIdx.x >> 3, ch = threadIdx.x & 7;
        #pragma unroll
        for (int it = 0; it < 8; ++it) {
            const int r = it * 32 + rr;
            if (t0 + r < T_LEN) {
                const uint4 v = *(const uint4*)(&S[r * 72 + 8 * ch]);
                *(uint4*)(rectT + ((size_t)(t0 + r)) * 256 + 64 * g + 8 * ch) = v;
            }
        }
    }
}
#undef HALF
#undef GROUP

__global__ __launch_bounds__(256, 2) void conv_mfma(
        const unsigned short* __restrict__ xc, const unsigned short* __restrict__ Afrag,
        const int* __restrict__ kstart, unsigned short* __restrict__ rectT,
        int L, int SMAXA, int PAD, int XCAP) {
    __shared__ __align__(16) short smem[256 * 72];     // union: As[2][PHASE*512] | S[256][72]
    const int g  = blockIdx.y;
    const int t0 = blockIdx.x * TTILE;
    const int ks = kstart[g * 16];
    if (g == 0) conv_body<16>(xc, Afrag, rectT, smem, L, SMAXA, PAD, XCAP, g, t0, ks);
    else        conv_body<8>(xc, Afrag, rectT, smem, L, SMAXA, PAD, XCAP, g, t0, ks);
}

// ---------------------------------------------------------------- K2: fused EMA + adaptive-threshold scan
static __device__ __forceinline__ float bfw(unsigned int w, int odd) {
    return __uint_as_float(odd ? (w & 0xFFFF0000u) : (w << 16));
}

__device__ __forceinline__ void scan_step(float r0, float r1, float r2, float r3,
        int u, bool store, int c, float* __restrict__ out0, float* __restrict__ out1,
        float& s0, float& s1, float& s2, float& s3, float& thr) {
    s0 = AF * r0 + OMF * s0;
    s1 = AF * r1 + OMF * s1;
    s2 = AF * r2 + OMF * s2;
    s3 = AF * r3 + OMF * s3;
    const float k0 = (s0 > thr) ? 1.0f : 0.0f;
    const float k1 = (s1 > thr) ? 1.0f : 0.0f;
    const float k2 = (s2 > thr) ? 1.0f : 0.0f;
    const float k3 = (s3 > thr) ? 1.0f : 0.0f;
    const float cnt = (k0 + k1) + (k2 + k3);
    thr = thr + 0.01f * (cnt * 0.25f) + 0.01f * (0.1f - thr);
    if (store) {
        const int e  = (u >= T_LEN) ? 1 : 0;
        const int tt = u - (e ? T_LEN : 0);
        const int o1 = ((e * T_LEN + tt) << 6) + c;          // [B][2][T][C]
        out1[o1]                   = s0;
        out1[o1 + 2 * T_LEN * NCH] = s1;
        out1[o1 + 4 * T_LEN * NCH] = s2;
        out1[o1 + 6 * T_LEN * NCH] = s3;
        const int o0 = (tt << 7) + (e << 6) + c;             // [B][T][2C]
        out0[o0]                   = k0;
        out0[o0 + T_LEN * 128]     = k1;
        out0[o0 + 2 * T_LEN * 128] = k2;
        out0[o0 + 3 * T_LEN * 128] = k3;
    }
}

// 16 steps per group; groups never straddle the ear boundary (96|48000, WU%16==0)
#define LOAD_G16(buf, ug) do {                                                       \
    const int tt_ = ((ug) < T_LEN) ? (ug) : ((ug) - T_LEN);                          \
    const unsigned short* bp_ = rectT + (size_t)tt_ * 256 + c * 4;                   \
    _Pragma("unroll")                                                                \
    for (int q_ = 0; q_ < 16; ++q_) buf[q_] = *(const uint2*)(bp_ + q_ * 256);       \
} while (0)

#define PROC_G16(buf, ug) do {                                                       \
    _Pragma("unroll")                                                                \
    for (int q_ = 0; q_ < 16; ++q_) {                                                \
        const float r0_ = bfw(buf[q_].x, 0);                                         \
        const float r1_ = bfw(buf[q_].x, 1);                                         \
        const float r2_ = bfw(buf[q_].y, 0);                                         \
        const float r3_ = bfw(buf[q_].y, 1);                                         \
        scan_step(r0_, r1_, r2_, r3_, (ug) + q_, STORE, c, out0, out1, s0, s1, s2, s3, thr); \
    }                                                                                \
} while (0)

template <bool STORE>
__device__ __forceinline__ void scan_range(int from, int to, int c,
        const unsigned short* __restrict__ rectT, float* __restrict__ out0, float* __restrict__ out1,
        float& s0, float& s1, float& s2, float& s3, float& thr) {
    if (from >= to) return;                // (to-from) is a multiple of 32
    uint2 bufA[16], bufB[16];
    LOAD_G16(bufA, from);
    for (int ug = from; ug < to; ug += 32) {
        LOAD_G16(bufB, ug + 16);
        PROC_G16(bufA, ug);
        if (ug + 32 < to) LOAD_G16(bufA, ug + 32);
        PROC_G16(bufB, ug + 16);
    }
}

__global__ __launch_bounds__(256) void scan_kernel(const unsigned short* __restrict__ rectT,
                                                   float* __restrict__ out) {
    const int k = blockIdx.x * 4 + (int)(threadIdx.x >> 6);   // chunk id
    if (k >= (2 * T_LEN) / CT) return;
    const int c    = threadIdx.x & 63;                  // channel
    const int u0   = k * CT;
    const int uend = u0 + CT;
    const int w0   = (u0 >= WU) ? (u0 - WU) : 0;
    float s0 = 0.f, s1 = 0.f, s2 = 0.f, s3 = 0.f, thr = 0.1f;
    float* out0 = out;
    float* out1 = out + (size_t)NB * T_LEN * 2 * NCH;   // 24,576,000
    scan_range<false>(w0, u0,   c, rectT, out0, out1, s0, s1, s2, s3, thr);
    scan_range<true >(u0, uend, c, rectT, out0, out1, s0, s1, s2, s3, thr);
}

// ---------------------------------------------------------------- launch
extern "C" void kernel_launch(void* const* d_in, const int* in_sizes, int n_in,
                              void* d_out, int out_size, void* d_ws, size_t ws_size,
                              hipStream_t stream) {
    const float* x  = (const float*)d_in[0];       // [4, 48000] fp32
    const float* Km = (const float*)d_in[1];       // [64, L]    fp32
    const int L      = in_sizes[1] / NCH;
    const int SMAX   = (L + 31) / 32;
    const int SMAX16 = (SMAX + 15) & ~15;
    const int SMAXA  = SMAX16 + 20;                // guard rows for A prefetch
    const int PAD    = (L + 1) & ~1;               // even, >= L-1
    const int XCAP   = PAD + T_LEN + 1024;         // even; covers padded-K over-read

    char* w = (char*)d_ws;
    int* kstart = (int*)w;
    unsigned short* xc = (unsigned short*)(w + 512);
    const size_t xc_bytes = (size_t)NB * 2 * XCAP * 2;
    unsigned short* Afrag = (unsigned short*)(w + 512 + ((xc_bytes + 15) & ~(size_t)15));
    const size_t a_bytes = (size_t)4 * SMAXA * 64 * 8 * 2;
    unsigned short* rectT = (unsigned short*)((char*)Afrag + ((a_bytes + 15) & ~(size_t)15));

    const int pxBlocks = (NB * XCAP + 255) / 256;
    dim3 pgrid(pxBlocks > SMAX16 ? pxBlocks : SMAX16, 5);
    prep_all<<<pgrid, 256, 0, stream>>>(x, Km, kstart, xc, Afrag, L, SMAX16, SMAXA, PAD, XCAP);
    conv_mfma<<<dim3((T_LEN + TTILE - 1) / TTILE, 4), 256, 0, stream>>>(
        xc, Afrag, kstart, rectT, L, SMAXA, PAD, XCAP);
    const int nchunks = (2 * T_LEN) / CT;          // 1000
    scan_kernel<<<(nchunks + 3) / 4, 256, 0, stream>>>(rectT, (float*)d_out);
}

// Round 16
// 84.401 us; speedup vs baseline: 1.0699x; 1.0699x over previous
//
#include <hip/hip_runtime.h>
#include <hip/hip_bf16.h>

#define T_LEN 48000
#define NCH   64
#define NB    4
#define CT    96     // scan chunk length (96000/96 = 1000 chunks; ear boundary = chunk 500)
#define WU    128    // scan warm-up (0.96^128=5.4e-3 -> s err ~0.47; thr err -> spike flips only)
#define TTILE 320    // conv time-span per block (20 MFMA tiles per wave, ring of 20)

static constexpr double DTd    = 1.0 / 48000.0;
static constexpr double ALPHAd = DTd / (DTd + 0.0005);   // exactly 0.04
static constexpr float  AF     = (float)ALPHAd;
static constexpr float  OMF    = (float)(1.0 - ALPHAd);  // 0.96

typedef __attribute__((ext_vector_type(8))) short bf16x8;
typedef __attribute__((ext_vector_type(4))) float f32x4;
typedef bf16x8 bf16x8_u __attribute__((aligned(4)));     // 4B-aligned 16B load

static __device__ __forceinline__ unsigned short f2bf(float f) {
    __hip_bfloat16 h = __float2bfloat16(f);
    unsigned short u; __builtin_memcpy(&u, &h, 2);
    return u;
}

// ---------------------------------------------------------------- K0: fused prep
// role 0..3: Afrag swizzle for group g (+kstart); role 4: x -> parity bf16 copies
__global__ __launch_bounds__(256) void prep_all(
        const float* __restrict__ x, const float* __restrict__ Km,
        int* __restrict__ kstart, unsigned short* __restrict__ xc,
        unsigned short* __restrict__ Afrag,
        int L, int SMAX10, int SMAXA, int PAD, int XCAP) {
    const int role = blockIdx.y;
    if (role < 4) {
        const int g = role, s = blockIdx.x;
        if (s >= SMAX10) return;
        __shared__ int smin;
        if (threadIdx.x == 0) smin = L - 1;
        __syncthreads();
        const float* row = Km + (size_t)(g * 16) * L;
        int local = L - 1;
        for (int i = threadIdx.x; i < L; i += 256)
            if (row[i] != 0.0f) { local = i; break; }
        atomicMin(&smin, local);
        __syncthreads();
        const int ks = smin;
        if (s == 0 && threadIdx.x == 0) kstart[g * 16] = ks;
        if (threadIdx.x < 64) {
            const int lane = threadIdx.x;
            const int Lg = L - ks;
            const int r = lane & 15, khi = lane >> 4;
            const float* kr = Km + (size_t)(g * 16 + r) * L + ks;
            const size_t off = ((size_t)(g * SMAXA + s) * 64 + lane) * 8;
            #pragma unroll
            for (int jj = 0; jj < 8; ++jj) {
                const int q = 32 * s + 8 * khi + jj;
                Afrag[off + jj] = (q < Lg) ? f2bf(kr[q]) : (unsigned short)0;
            }
        }
    } else {
        const int idx = blockIdx.x * 256 + threadIdx.x;
        if (idx >= NB * XCAP) return;
        const int b = idx / XCAP, j = idx % XCAP;
        const float* xb = x + (size_t)b * T_LEN;
        const int t0 = j - PAD, t1 = t0 + 1;
        xc[((size_t)b * 2 + 0) * XCAP + j] = (t0 >= 0 && t0 < T_LEN) ? f2bf(xb[t0]) : (unsigned short)0;
        xc[((size_t)b * 2 + 1) * XCAP + j] = (t1 >= 0 && t1 < T_LEN) ? f2bf(xb[t1]) : (unsigned short)0;
    }
}

// ---------------------------------------------------------------- K1: MFMA filterbank -> rectT [T][C*4+B]
// Ring of 20 B-windows, 10-K-step phases (20 windows/phase == 0 mod 20 -> slot
// map (2U+j)%20 is phase-invariant). 20 MFMA per 2 B-loads (-24% TA pressure
// vs ring-16). A staged via double-buffered LDS; refills issued right after the
// two releasing MFMAs of each GROUP (window 2U+20 first used 18 MFMA later).
__global__ __launch_bounds__(256, 2) void conv_mfma(
        const unsigned short* __restrict__ xc, const unsigned short* __restrict__ Afrag,
        const int* __restrict__ kstart, unsigned short* __restrict__ rectT,
        int L, int SMAXA, int PAD, int XCAP) {
    const int lane = threadIdx.x & 63;
    const int w    = threadIdx.x >> 6;                 // wave = batch
    const int g    = blockIdx.y;
    const int t0   = blockIdx.x * TTILE;
    const int ks   = kstart[g * 16];
    const int Lg   = L - ks;
    const int nst  = (Lg + 31) >> 5;
    const int nstP = ((nst + 9) / 10) * 10;            // K-steps, padded to x10 (A zero rows)
    const int nl   = lane & 15, khi = lane >> 4;
    const int i0   = t0 + nl + 8 * khi - (Lg - 1);     // x index for (K-step 0, tile 0)
    const int p    = i0 & 1;                           // parity fixed across steps/tiles
    const unsigned short* xp  = xc + ((size_t)(w * 2 + p)) * XCAP + (PAD + i0 - p);
    // wave w stages A K-step rows rb..rb+2 per phase (rows 7,8 double-written, benign)
    const int rb = (w == 3) ? 7 : 3 * w;
    const unsigned short* apw = Afrag + ((size_t)(g * SMAXA) + rb) * 512 + (size_t)lane * 8;

    __shared__ __align__(16) short smem[TTILE * 72];   // union: As[2][10*512] (20KB) | S[320][72] (45KB)
    short* As = smem;

    f32x4 acc[20];
    #pragma unroll
    for (int j = 0; j < 20; ++j) acc[j] = (f32x4){0.f, 0.f, 0.f, 0.f};
    bf16x8 bx[20];
    #pragma unroll
    for (int j = 0; j < 20; ++j) bx[j] = *(const bf16x8_u*)(xp + 16 * j);

    {   // initial stage: K-step rows 0..9
        const bf16x8 s0 = *(const bf16x8*)(apw);
        const bf16x8 s1 = *(const bf16x8*)(apw + 512);
        const bf16x8 s2 = *(const bf16x8*)(apw + 1024);
        *(bf16x8*)(&As[(rb)     * 512 + lane * 8]) = s0;
        *(bf16x8*)(&As[(rb + 1) * 512 + lane * 8]) = s1;
        *(bf16x8*)(&As[(rb + 2) * 512 + lane * 8]) = s2;
    }
    __syncthreads();

// K-step U (0..9) of phase: tile j uses slot (2U+j)%20; slots (2U)%20,(2U+1)%20
// are released at j=0,1 -> refill with windows 2U+20, 2U+21 (elems 320+32U, 336+32U).
#define GROUP(areg, U)                                                                   \
    acc[0] = __builtin_amdgcn_mfma_f32_16x16x32_bf16(areg, bx[(2*(U))     % 20], acc[0], 0, 0, 0); \
    acc[1] = __builtin_amdgcn_mfma_f32_16x16x32_bf16(areg, bx[(2*(U) + 1) % 20], acc[1], 0, 0, 0); \
    bx[(2*(U))     % 20] = *(const bf16x8_u*)(xp + 320 + 32 * (U));                      \
    bx[(2*(U) + 1) % 20] = *(const bf16x8_u*)(xp + 336 + 32 * (U));                      \
    _Pragma("unroll")                                                                    \
    for (int j = 2; j < 20; ++j)                                                         \
        acc[j] = __builtin_amdgcn_mfma_f32_16x16x32_bf16(areg, bx[(2*(U) + j) % 20], acc[j], 0, 0, 0);

    int q = 0;
    for (int s = 0; s < nstP; s += 10) {
        // prefetch next phase's 3 A rows (guard rows exist beyond nstP)
        const bf16x8 n0 = *(const bf16x8*)(apw + (size_t)(s + 10) * 512);
        const bf16x8 n1 = *(const bf16x8*)(apw + (size_t)(s + 11) * 512);
        const bf16x8 n2 = *(const bf16x8*)(apw + (size_t)(s + 12) * 512);
        const short* Ab = As + q * 5120;
        {   // K-steps 0..3 of the phase
            const bf16x8 a0 = *(const bf16x8*)(&Ab[       lane * 8]);
            const bf16x8 a1 = *(const bf16x8*)(&Ab[ 512 + lane * 8]);
            const bf16x8 a2 = *(const bf16x8*)(&Ab[1024 + lane * 8]);
            const bf16x8 a3 = *(const bf16x8*)(&Ab[1536 + lane * 8]);
            GROUP(a0, 0)
            GROUP(a1, 1)
            GROUP(a2, 2)
            GROUP(a3, 3)
        }
        {   // K-steps 4..7
            const bf16x8 a4 = *(const bf16x8*)(&Ab[2048 + lane * 8]);
            const bf16x8 a5 = *(const bf16x8*)(&Ab[2560 + lane * 8]);
            const bf16x8 a6 = *(const bf16x8*)(&Ab[3072 + lane * 8]);
            const bf16x8 a7 = *(const bf16x8*)(&Ab[3584 + lane * 8]);
            GROUP(a4, 4)
            GROUP(a5, 5)
            GROUP(a6, 6)
            GROUP(a7, 7)
        }
        {   // K-steps 8..9
            const bf16x8 a8 = *(const bf16x8*)(&Ab[4096 + lane * 8]);
            const bf16x8 a9 = *(const bf16x8*)(&Ab[4608 + lane * 8]);
            GROUP(a8, 8)
            GROUP(a9, 9)
        }
        // stage next phase's A rows into the other buffer, block-wide handoff
        *(bf16x8*)(&As[(q ^ 1) * 5120 + (rb)     * 512 + lane * 8]) = n0;
        *(bf16x8*)(&As[(q ^ 1) * 5120 + (rb + 1) * 512 + lane * 8]) = n1;
        *(bf16x8*)(&As[(q ^ 1) * 5120 + (rb + 2) * 512 + lane * 8]) = n2;
        __syncthreads();
        q ^= 1;
        xp += 320;                                     // 10 K-steps x 32 taps
    }
#undef GROUP

    // ---- epilogue: acc -> S[t_local][(c_local)*4 + b] -> rectT rows ----
    // D layout: col(time)=lane&15, row(channel)=4*(lane>>4)+v  [m89-verified]
    short* S = smem;                                   // stride 72 shorts/row (16B-mult)
    #pragma unroll
    for (int j = 0; j < 20; ++j) {
        #pragma unroll
        for (int v = 0; v < 4; ++v)
            S[(16 * j + nl) * 72 + (4 * khi + v) * 4 + w] =
                (short)f2bf(fmaxf(acc[j][v], 0.f));
    }
    __syncthreads();
    {   // cooperative copy: 10 iters x 32 rows; 128B contiguous per row-segment
        const int rr = threadIdx.x >> 3, ch = threadIdx.x & 7;
        #pragma unroll
        for (int it = 0; it < 10; ++it) {
            const int r = it * 32 + rr;
            const uint4 v = *(const uint4*)(&S[r * 72 + 8 * ch]);
            *(uint4*)(rectT + ((size_t)(t0 + r)) * 256 + 64 * g + 8 * ch) = v;
        }
    }
}

// ---------------------------------------------------------------- K2: fused EMA + adaptive-threshold scan
static __device__ __forceinline__ float bfw(unsigned int w, int odd) {
    return __uint_as_float(odd ? (w & 0xFFFF0000u) : (w << 16));
}

__device__ __forceinline__ void scan_step(float r0, float r1, float r2, float r3,
        int u, bool store, int c, float* __restrict__ out0, float* __restrict__ out1,
        float& s0, float& s1, float& s2, float& s3, float& thr) {
    s0 = AF * r0 + OMF * s0;
    s1 = AF * r1 + OMF * s1;
    s2 = AF * r2 + OMF * s2;
    s3 = AF * r3 + OMF * s3;
    const float k0 = (s0 > thr) ? 1.0f : 0.0f;
    const float k1 = (s1 > thr) ? 1.0f : 0.0f;
    const float k2 = (s2 > thr) ? 1.0f : 0.0f;
    const float k3 = (s3 > thr) ? 1.0f : 0.0f;
    const float cnt = (k0 + k1) + (k2 + k3);
    thr = thr + 0.01f * (cnt * 0.25f) + 0.01f * (0.1f - thr);
    if (store) {
        const int e  = (u >= T_LEN) ? 1 : 0;
        const int tt = u - (e ? T_LEN : 0);
        const int o1 = ((e * T_LEN + tt) << 6) + c;          // [B][2][T][C]
        out1[o1]                   = s0;
        out1[o1 + 2 * T_LEN * NCH] = s1;
        out1[o1 + 4 * T_LEN * NCH] = s2;
        out1[o1 + 6 * T_LEN * NCH] = s3;
        const int o0 = (tt << 7) + (e << 6) + c;             // [B][T][2C]
        out0[o0]                   = k0;
        out0[o0 + T_LEN * 128]     = k1;
        out0[o0 + 2 * T_LEN * 128] = k2;
        out0[o0 + 3 * T_LEN * 128] = k3;
    }
}

// 16 steps per group; groups never straddle the ear boundary (96|48000, WU%16==0)
#define LOAD_G16(buf, ug) do {                                                       \
    const int tt_ = ((ug) < T_LEN) ? (ug) : ((ug) - T_LEN);                          \
    const unsigned short* bp_ = rectT + (size_t)tt_ * 256 + c * 4;                   \
    _Pragma("unroll")                                                                \
    for (int q_ = 0; q_ < 16; ++q_) buf[q_] = *(const uint2*)(bp_ + q_ * 256);       \
} while (0)

#define PROC_G16(buf, ug) do {                                                       \
    _Pragma("unroll")                                                                \
    for (int q_ = 0; q_ < 16; ++q_) {                                                \
        const float r0_ = bfw(buf[q_].x, 0);                                         \
        const float r1_ = bfw(buf[q_].x, 1);                                         \
        const float r2_ = bfw(buf[q_].y, 0);                                         \
        const float r3_ = bfw(buf[q_].y, 1);                                         \
        scan_step(r0_, r1_, r2_, r3_, (ug) + q_, STORE, c, out0, out1, s0, s1, s2, s3, thr); \
    }                                                                                \
} while (0)

template <bool STORE>
__device__ __forceinline__ void scan_range(int from, int to, int c,
        const unsigned short* __restrict__ rectT, float* __restrict__ out0, float* __restrict__ out1,
        float& s0, float& s1, float& s2, float& s3, float& thr) {
    if (from >= to) return;                // (to-from) is a multiple of 32
    uint2 bufA[16], bufB[16];
    LOAD_G16(bufA, from);
    for (int ug = from; ug < to; ug += 32) {
        LOAD_G16(bufB, ug + 16);
        PROC_G16(bufA, ug);
        if (ug + 32 < to) LOAD_G16(bufA, ug + 32);
        PROC_G16(bufB, ug + 16);
    }
}

__global__ __launch_bounds__(256) void scan_kernel(const unsigned short* __restrict__ rectT,
                                                   float* __restrict__ out) {
    const int k = blockIdx.x * 4 + (int)(threadIdx.x >> 6);   // chunk id
    if (k >= (2 * T_LEN) / CT) return;
    const int c    = threadIdx.x & 63;                  // channel
    const int u0   = k * CT;
    const int uend = u0 + CT;
    const int w0   = (u0 >= WU) ? (u0 - WU) : 0;
    float s0 = 0.f, s1 = 0.f, s2 = 0.f, s3 = 0.f, thr = 0.1f;
    float* out0 = out;
    float* out1 = out + (size_t)NB * T_LEN * 2 * NCH;   // 24,576,000
    scan_range<false>(w0, u0,   c, rectT, out0, out1, s0, s1, s2, s3, thr);
    scan_range<true >(u0, uend, c, rectT, out0, out1, s0, s1, s2, s3, thr);
}

// ---------------------------------------------------------------- launch
extern "C" void kernel_launch(void* const* d_in, const int* in_sizes, int n_in,
                              void* d_out, int out_size, void* d_ws, size_t ws_size,
                              hipStream_t stream) {
    const float* x  = (const float*)d_in[0];       // [4, 48000] fp32
    const float* Km = (const float*)d_in[1];       // [64, L]    fp32
    const int L      = in_sizes[1] / NCH;
    const int SMAX   = (L + 31) / 32;
    const int SMAX10 = ((SMAX + 9) / 10) * 10;
    const int SMAXA  = SMAX10 + 16;                // guard rows for A prefetch
    const int PAD    = (L + 1) & ~1;               // even, >= L-1
    const int XCAP   = PAD + T_LEN + 1024;         // even; covers padded-K over-read

    char* w = (char*)d_ws;
    int* kstart = (int*)w;
    unsigned short* xc = (unsigned short*)(w + 512);
    const size_t xc_bytes = (size_t)NB * 2 * XCAP * 2;
    unsigned short* Afrag = (unsigned short*)(w + 512 + ((xc_bytes + 15) & ~(size_t)15));
    const size_t a_bytes = (size_t)4 * SMAXA * 64 * 8 * 2;
    unsigned short* rectT = (unsigned short*)((char*)Afrag + ((a_bytes + 15) & ~(size_t)15));

    const int pxBlocks = (NB * XCAP + 255) / 256;
    dim3 pgrid(pxBlocks > SMAX10 ? pxBlocks : SMAX10, 5);
    prep_all<<<pgrid, 256, 0, stream>>>(x, Km, kstart, xc, Afrag, L, SMAX10, SMAXA, PAD, XCAP);
    conv_mfma<<<dim3(T_LEN / TTILE, 4), 256, 0, stream>>>(
        xc, Afrag, kstart, rectT, L, SMAXA, PAD, XCAP);
    const int nchunks = (2 * T_LEN) / CT;          // 1000
    scan_kernel<<<(nchunks + 3) / 4, 256, 0, stream>>>(rectT, (float*)d_out);
}